// Round 10
// baseline (185.763 us; speedup 1.0000x reference)
//
#include <hip/hip_runtime.h>
#include <math.h>
#include <stdint.h>

typedef unsigned __int128 u128;

#define NK 10000
#define NDRAW 30100
#define NROW 3

#define PCG_MUL_128 ((((u128)0x2360ed051fc65da4ULL) << 64) | 0x4385df649fccf645ULL)

__device__ int   g_sel;
__device__ float g_diag;

// ============================================================================
// HOST-SIDE numpy default_rng(0) chain (verified r8/r9):
// SeedSequence mix() = x*L - y*R (SUBTRACT); PCG64 XSL-RR step-then-output.
// ============================================================================
static void build_stream(uint64_t* out) {
  uint32_t w[8];
  uint32_t hc = 0x43b0d7e5u;                                  // INIT_A
  auto hashmix = [&hc](uint32_t v) -> uint32_t {
    v ^= hc; hc *= 0x931e8875u; v *= hc; v ^= v >> 16; return v;   // MULT_A
  };
  uint32_t pool[4];
  for (int i = 0; i < 4; ++i) pool[i] = hashmix(0u);          // entropy=[0]
  for (int s = 0; s < 4; ++s)
    for (int d = 0; d < 4; ++d)
      if (s != d) {
        uint32_t h = hashmix(pool[s]);
        uint32_t r = pool[d] * 0xca01f9ddu - h * 0x4973f715u; // MIX: subtract
        r ^= r >> 16;
        pool[d] = r;
      }
  uint32_t hb = 0x8b51f9ddu;                                  // INIT_B
  for (int i = 0; i < 8; ++i) {
    uint32_t v = pool[i & 3];
    v ^= hb; hb *= 0x58f38dedu; v *= hb; v ^= v >> 16;        // MULT_B
    w[i] = v;
  }
  uint64_t A = (uint64_t)w[0] | ((uint64_t)w[1] << 32);
  uint64_t B = (uint64_t)w[2] | ((uint64_t)w[3] << 32);
  uint64_t C = (uint64_t)w[4] | ((uint64_t)w[5] << 32);
  uint64_t D = (uint64_t)w[6] | ((uint64_t)w[7] << 32);
  u128 initstate = ((u128)A << 64) | B;
  u128 initseq   = ((u128)C << 64) | D;
  u128 inc = (initseq << 1) | (u128)1;
  u128 st  = inc;                    // srandom from state=0
  st += initstate;
  st = st * PCG_MUL_128 + inc;
  for (int i = 0; i < NDRAW; ++i) {  // step-then-output XSL-RR
    st = st * PCG_MUL_128 + inc;
    uint64_t x = (uint64_t)(st >> 64) ^ (uint64_t)st;
    unsigned r = (unsigned)(st >> 122);
    out[i] = (x >> r) | (x << ((64u - r) & 63u));
  }
}

struct HCur { const uint64_t* s; int pos; int has; uint32_t buf; int hifirst; };
static inline uint32_t hnext32(HCur& c) {
  if (c.has) { c.has = 0; return c.buf; }
  uint64_t v = c.s[c.pos++]; c.has = 1;
  if (c.hifirst) { c.buf = (uint32_t)v; return (uint32_t)(v >> 32); }
  c.buf = (uint32_t)(v >> 32); return (uint32_t)v;
}

static int t_ks[NK];
// structures: 1 = Lemire64 (dtype=int64 default), 0 = Lemire32-lo, 2 = Lemire32-hi
static void gen_combo(const uint64_t* st, int s, uint16_t* dst) {
  HCur c{st, 0, 0, 0, (s == 2) ? 1 : 0};
  for (int i = 0; i < NK; ++i) {          // Phase 1: integers(0,3), Lemire
    if (s == 1)      { u128 m; do { m = (u128)st[c.pos++] * 3; } while ((uint64_t)m == 0);
                       t_ks[i] = (int)(uint64_t)(m >> 64); }
    else             { uint64_t m; do { m = (uint64_t)hnext32(c) * 3ull; } while ((uint32_t)m == 0u);
                       t_ks[i] = (int)(m >> 32); }
  }
  c.has = 0;
  for (int i = 0; i < NK; ++i) {          // Phase 2: uniform(0,hi) -> floor(2**u)
    double d = (double)(st[c.pos++] >> 11) * (1.0 / 9007199254740992.0);
    int ks = 7 + 2 * t_ks[i];
    int m  = 511 / (ks - 1);              // 85 / 63 / 51
    double u = log2((double)m) * d;       // glibc == numpy's libm
    int dil = (int)floor(pow(2.0, u));    // 1..84
    dst[i] = (uint16_t)((uint32_t)t_ks[i] | ((uint32_t)(dil & 127) << 2));
  }
  c.has = 0;
  for (int i = 0; i < NK; ++i) {          // Phase 3: integers(0,2): MSB
    int pad;
    if (s == 1) pad = (int)(st[c.pos++] >> 63);
    else        pad = (int)(hnext32(c) >> 31);
    dst[i] = (uint16_t)(dst[i] | ((uint32_t)pad << 9));
  }
}

// ============================================================================
// Device: selection only -- find first row matching ks ground truth from W
// ============================================================================
__global__ __launch_bounds__(1024) void select_k(const float* __restrict__ W,
                                                 const uint16_t* __restrict__ cand,
                                                 float failDiag) {
  __shared__ int ksW[NK];
  __shared__ int mism[NROW];
  int tid = threadIdx.x;
  for (int i = tid; i < NK; i += 1024) {
    float w10 = W[i * 11 + 10], w8 = W[i * 11 + 8];
    ksW[i] = (w10 != 0.0f) ? 11 : ((w8 != 0.0f) ? 9 : 7);
  }
  if (tid < NROW) mism[tid] = 0;
  __syncthreads();
  for (int c = 0; c < NROW; ++c) {
    int bad = 0;
    for (int i = tid; i < NK; i += 1024) {
      int ks = 7 + 2 * (int)(cand[c * NK + i] & 3);
      if (ks != ksW[i]) { bad = 1; break; }
    }
    if (bad) atomicExch(&mism[c], 1);
  }
  __syncthreads();
  if (tid == 0) {
    int sel = -1;
    for (int c = 0; c < NROW; ++c) if (!mism[c]) { sel = c; break; }
    g_sel = sel;
    g_diag = (sel >= 0) ? 0.0f : failDiag;
  }
}

// ============================================================================
// Main conv + max/ppv kernel: one block (512 thr, 8 waves) per output kernel k.
// Core uses 4-way strided t-blocking (t, t+64, t+128, t+192 per lane): per tap
// one shared vaddr + ds_read2-mergeable offsets 0/64/128/192 dwords, zero bank
// conflicts (each sub-read is lane-stride-1).
// ============================================================================
template<int KS>
__device__ __forceinline__ void conv_batch(const float* __restrict__ xr, const float* wv,
                                           float bv, int twop, int dil, int L, int lane,
                                           float& vmax, int& cnt) {
  // guarded prologue: t in [0, twop)   (empty when pad==0)
  for (int t = lane; t < twop; t += 64) {
    float acc = bv;
    int idx = t - twop;
    #pragma unroll
    for (int j = 0; j < KS; ++j) {
      int ci = idx < 0 ? 0 : idx;
      acc = fmaf(wv[j], ((unsigned)idx < 512u) ? xr[ci] : 0.0f, acc);
      idx += dil;
    }
    vmax = fmaxf(vmax, acc);
    cnt += (acc > 0.0f);
  }
  // core: t in [twop, min(L,512)) -- all taps in-range (see in-range proof):
  //   pad=1: idx = t - twop + j*dil <= t <= 511 ; pad=0: idx < L + (KS-1)*dil = 512
  int coreEnd = (L < 512) ? L : 512;
  int base = twop;
  int rem = coreEnd - twop;
  for (; rem >= 256; base += 256, rem -= 256) {      // 4-way blocks
    const float* p = xr + (base - twop) + lane;
    float a0 = bv, a1 = bv, a2 = bv, a3 = bv;
    int idx = 0;
    #pragma unroll
    for (int j = 0; j < KS; ++j) {
      a0 = fmaf(wv[j], p[idx], a0);
      a1 = fmaf(wv[j], p[idx + 64], a1);
      a2 = fmaf(wv[j], p[idx + 128], a2);
      a3 = fmaf(wv[j], p[idx + 192], a3);
      idx += dil;
    }
    vmax = fmaxf(vmax, fmaxf(fmaxf(a0, a1), fmaxf(a2, a3)));
    cnt += (a0 > 0.0f); cnt += (a1 > 0.0f); cnt += (a2 > 0.0f); cnt += (a3 > 0.0f);
  }
  if (rem >= 128) {                                   // one 2-way block
    const float* p = xr + (base - twop) + lane;
    float a0 = bv, a1 = bv;
    int idx = 0;
    #pragma unroll
    for (int j = 0; j < KS; ++j) {
      a0 = fmaf(wv[j], p[idx], a0);
      a1 = fmaf(wv[j], p[idx + 64], a1);
      idx += dil;
    }
    vmax = fmaxf(vmax, fmaxf(a0, a1));
    cnt += (a0 > 0.0f); cnt += (a1 > 0.0f);
    base += 128; rem -= 128;
  }
  for (int t = base + lane; t < coreEnd; t += 64) {   // scalar core tail (<128 t)
    float acc = bv;
    const float* p = xr + (t - twop);
    int idx = 0;
    #pragma unroll
    for (int j = 0; j < KS; ++j) { acc = fmaf(wv[j], p[idx], acc); idx += dil; }
    vmax = fmaxf(vmax, acc);
    cnt += (acc > 0.0f);
  }
  // guarded epilogue: t in [512, L)   (empty when pad==0)
  for (int t = 512 + lane; t < L; t += 64) {
    float acc = bv;
    int idx = t - twop;
    #pragma unroll
    for (int j = 0; j < KS; ++j) {
      int ci = idx > 511 ? 511 : idx;
      acc = fmaf(wv[j], ((unsigned)idx < 512u) ? xr[ci] : 0.0f, acc);
      idx += dil;
    }
    vmax = fmaxf(vmax, acc);
    cnt += (acc > 0.0f);
  }
}

__global__ __launch_bounds__(512) void conv_feat_k(const float* __restrict__ x,
                                                   const float* __restrict__ W,
                                                   const float* __restrict__ bias,
                                                   const uint16_t* __restrict__ cand,
                                                   float* __restrict__ out) {
  __shared__ float xs[16 * 512];
  int k = blockIdx.x;
  int tid = threadIdx.x;
  const float4* x4 = (const float4*)x;
  float4* xs4 = (float4*)xs;
  #pragma unroll
  for (int i = 0; i < 4; ++i)
    xs4[tid + 512 * i] = x4[tid + 512 * i];

  int sel = g_sel;
  float diag = g_diag;
  int ks = 0, dil = 1, twop = 0, L = 1;
  if (sel >= 0) {
    uint32_t wd = cand[sel * NK + k];
    ks = 7 + 2 * (int)(wd & 3);
    dil = (int)((wd >> 2) & 127);
    int pad = (int)(wd >> 9);
    twop = (ks - 1) * dil * pad;
    L = 512 + 2 * twop - dil * (ks - 1);
  }
  float wv[11];
  #pragma unroll
  for (int j = 0; j < 11; ++j) wv[j] = W[k * 11 + j];
  float bv = bias[k];
  __syncthreads();

  int wave = tid >> 6, lane = tid & 63;
  for (int bb = wave; bb < 16; bb += 8) {
    if (ks == 0) {   // diagnostic path (never taken when RNG matches)
      if (lane == 0) {
        out[(size_t)bb * 20000 + 2 * k]     = diag;
        out[(size_t)bb * 20000 + 2 * k + 1] = diag;
      }
      continue;
    }
    const float* xr = xs + bb * 512;
    float vmax = -INFINITY;
    int cnt = 0;
    if (ks == 7)       conv_batch<7>(xr, wv, bv, twop, dil, L, lane, vmax, cnt);
    else if (ks == 9)  conv_batch<9>(xr, wv, bv, twop, dil, L, lane, vmax, cnt);
    else               conv_batch<11>(xr, wv, bv, twop, dil, L, lane, vmax, cnt);
    #pragma unroll
    for (int off = 32; off >= 1; off >>= 1) {
      vmax = fmaxf(vmax, __shfl_xor(vmax, off));
      cnt += __shfl_xor(cnt, off);
    }
    if (lane == 0) {
      out[(size_t)bb * 20000 + 2 * k]     = vmax;
      out[(size_t)bb * 20000 + 2 * k + 1] = (float)cnt / (float)L;
    }
  }
}

extern "C" void kernel_launch(void* const* d_in, const int* in_sizes, int n_in,
                              void* d_out, int out_size, void* d_ws, size_t ws_size,
                              hipStream_t stream) {
  (void)out_size; (void)ws_size;
  const float *x = nullptr, *W = nullptr, *bias = nullptr;
  for (int i = 0; i < n_in; ++i) {
    int sz = in_sizes[i];
    if (sz == 16 * 512)      x    = (const float*)d_in[i];
    else if (sz == NK * 11)  W    = (const float*)d_in[i];
    else if (sz == NK)       bias = (const float*)d_in[i];
  }
  float failDiag = 0.0f;
  if (!x || !W || !bias) {
    failDiag = 9000000.0f;
    x = (const float*)d_in[0]; W = (const float*)d_in[1]; bias = (const float*)d_in[2];
  }

  static uint64_t s_sub[NDRAW];
  build_stream(s_sub);

  // d0 oracle: default_rng(0).random() == 0.6369616873214543 (verified r8)
  double d0 = (double)(s_sub[0] >> 11) * (1.0 / 9007199254740992.0);
  int d0ok = (fabs(d0 - 0.6369616873214543) < 1.0e-15) ? 1 : 0;
  if (failDiag == 0.0f) failDiag = d0ok ? 6000000.0f : 4000000.0f;

  // 3 candidate rows: {Lemire64 (analytic truth), Lemire32-lo, Lemire32-hi}
  static uint16_t h_cand[NROW * NK];
  gen_combo(s_sub, 1, h_cand + 0 * NK);
  gen_combo(s_sub, 0, h_cand + 1 * NK);
  gen_combo(s_sub, 2, h_cand + 2 * NK);

  hipMemcpyAsync(d_ws, h_cand, sizeof(h_cand), hipMemcpyHostToDevice, stream);
  select_k<<<1, 1024, 0, stream>>>(W, (const uint16_t*)d_ws, failDiag);
  conv_feat_k<<<NK, 512, 0, stream>>>(x, W, bias, (const uint16_t*)d_ws, (float*)d_out);
}

// Round 12
// 180.894 us; speedup vs baseline: 1.0269x; 1.0269x over previous
//
#include <hip/hip_runtime.h>
#include <math.h>
#include <stdint.h>

typedef unsigned __int128 u128;

#define NK 10000
#define NDRAW 30100
#define NROW 3

#define PCG_MUL_128 ((((u128)0x2360ed051fc65da4ULL) << 64) | 0x4385df649fccf645ULL)

__device__ int   g_sel;
__device__ float g_diag;

// ============================================================================
// HOST-SIDE numpy default_rng(0) chain (verified r8-r10):
// SeedSequence mix() = x*L - y*R (SUBTRACT); PCG64 XSL-RR step-then-output.
// Consumption (r11 post-mortem): rng<=2^32 -> buffered_bounded_lemire_uint32,
// pcg64_next32 = LOW half first, high buffered  => Lemire32-lo is row 0.
// ============================================================================
static void build_stream(uint64_t* out) {
  uint32_t w[8];
  uint32_t hc = 0x43b0d7e5u;                                  // INIT_A
  auto hashmix = [&hc](uint32_t v) -> uint32_t {
    v ^= hc; hc *= 0x931e8875u; v *= hc; v ^= v >> 16; return v;   // MULT_A
  };
  uint32_t pool[4];
  for (int i = 0; i < 4; ++i) pool[i] = hashmix(0u);          // entropy=[0]
  for (int s = 0; s < 4; ++s)
    for (int d = 0; d < 4; ++d)
      if (s != d) {
        uint32_t h = hashmix(pool[s]);
        uint32_t r = pool[d] * 0xca01f9ddu - h * 0x4973f715u; // MIX: subtract
        r ^= r >> 16;
        pool[d] = r;
      }
  uint32_t hb = 0x8b51f9ddu;                                  // INIT_B
  for (int i = 0; i < 8; ++i) {
    uint32_t v = pool[i & 3];
    v ^= hb; hb *= 0x58f38dedu; v *= hb; v ^= v >> 16;        // MULT_B
    w[i] = v;
  }
  uint64_t A = (uint64_t)w[0] | ((uint64_t)w[1] << 32);
  uint64_t B = (uint64_t)w[2] | ((uint64_t)w[3] << 32);
  uint64_t C = (uint64_t)w[4] | ((uint64_t)w[5] << 32);
  uint64_t D = (uint64_t)w[6] | ((uint64_t)w[7] << 32);
  u128 initstate = ((u128)A << 64) | B;
  u128 initseq   = ((u128)C << 64) | D;
  u128 inc = (initseq << 1) | (u128)1;
  u128 st  = inc;                    // srandom from state=0
  st += initstate;
  st = st * PCG_MUL_128 + inc;
  for (int i = 0; i < NDRAW; ++i) {  // step-then-output XSL-RR
    st = st * PCG_MUL_128 + inc;
    uint64_t x = (uint64_t)(st >> 64) ^ (uint64_t)st;
    unsigned r = (unsigned)(st >> 122);
    out[i] = (x >> r) | (x << ((64u - r) & 63u));
  }
}

struct HCur { const uint64_t* s; int pos; int has; uint32_t buf; int hifirst; };
static inline uint32_t hnext32(HCur& c) {
  if (c.has) { c.has = 0; return c.buf; }
  uint64_t v = c.s[c.pos++]; c.has = 1;
  if (c.hifirst) { c.buf = (uint32_t)v; return (uint32_t)(v >> 32); }
  c.buf = (uint32_t)(v >> 32); return (uint32_t)v;
}

static int t_ks[NK];
// structures: 0 = Lemire32-lo (numpy truth), 2 = Lemire32-hi, 1 = Lemire64
static void gen_combo(const uint64_t* st, int s, uint16_t* dst) {
  HCur c{st, 0, 0, 0, (s == 2) ? 1 : 0};
  for (int i = 0; i < NK; ++i) {          // Phase 1: integers(0,3), Lemire
    if (s == 1)      { u128 m; do { m = (u128)st[c.pos++] * 3; } while ((uint64_t)m == 0);
                       t_ks[i] = (int)(uint64_t)(m >> 64); }
    else             { uint64_t m; do { m = (uint64_t)hnext32(c) * 3ull; } while ((uint32_t)m == 0u);
                       t_ks[i] = (int)(m >> 32); }
  }
  c.has = 0;                              // (buffer empty: even u32 count)
  for (int i = 0; i < NK; ++i) {          // Phase 2: uniform(0,hi) -> floor(2**u)
    double d = (double)(st[c.pos++] >> 11) * (1.0 / 9007199254740992.0);
    int ks = 7 + 2 * t_ks[i];
    int m  = 511 / (ks - 1);              // 85 / 63 / 51
    double u = log2((double)m) * d;       // glibc == numpy's libm
    int dil = (int)floor(pow(2.0, u));    // 1..84
    dst[i] = (uint16_t)((uint32_t)t_ks[i] | ((uint32_t)(dil & 127) << 2));
  }
  c.has = 0;
  for (int i = 0; i < NK; ++i) {          // Phase 3: integers(0,2): MSB, no reject
    int pad;
    if (s == 1) pad = (int)(st[c.pos++] >> 63);
    else        pad = (int)(hnext32(c) >> 31);
    dst[i] = (uint16_t)(dst[i] | ((uint32_t)pad << 9));
  }
}

// ============================================================================
// Device: selection only -- first row matching ks ground truth from W
// ============================================================================
__global__ __launch_bounds__(1024) void select_k(const float* __restrict__ W,
                                                 const uint16_t* __restrict__ cand,
                                                 float failDiag) {
  __shared__ int ksW[NK];
  __shared__ int mism[NROW];
  int tid = threadIdx.x;
  for (int i = tid; i < NK; i += 1024) {
    float w10 = W[i * 11 + 10], w8 = W[i * 11 + 8];
    ksW[i] = (w10 != 0.0f) ? 11 : ((w8 != 0.0f) ? 9 : 7);
  }
  if (tid < NROW) mism[tid] = 0;
  __syncthreads();
  for (int c = 0; c < NROW; ++c) {
    int bad = 0;
    for (int i = tid; i < NK; i += 1024) {
      int ks = 7 + 2 * (int)(cand[c * NK + i] & 3);
      if (ks != ksW[i]) { bad = 1; break; }
    }
    if (bad) atomicExch(&mism[c], 1);
  }
  __syncthreads();
  if (tid == 0) {
    int sel = -1;
    for (int c = 0; c < NROW; ++c) if (!mism[c]) { sel = c; break; }
    g_sel = sel;
    g_diag = (sel >= 0) ? 0.0f : ((failDiag != 0.0f) ? failDiag : 6000000.0f);
  }
}

// ============================================================================
// Main conv + max/ppv kernel: one block (512 thr, 8 waves) per output kernel k.
// Core pairs adjacent t's per lane (t0, t0+1): per tap both reads share one
// base address with dword offsets 0,1 -> one ds_read2_b32 (halves DS insts).
// ============================================================================
template<int KS>
__device__ __forceinline__ void conv_batch(const float* __restrict__ xr, const float* wv,
                                           float bv, int twop, int dil, int L, int lane,
                                           float& vmax, int& cnt) {
  // guarded prologue: t in [0, twop)   (empty when pad==0)
  for (int t = lane; t < twop; t += 64) {
    float acc = bv;
    int idx = t - twop;
    #pragma unroll
    for (int j = 0; j < KS; ++j) {
      int ci = idx < 0 ? 0 : idx;
      acc = fmaf(wv[j], ((unsigned)idx < 512u) ? xr[ci] : 0.0f, acc);
      idx += dil;
    }
    vmax = fmaxf(vmax, acc);
    cnt += (acc > 0.0f);
  }
  // core: t in [twop, min(L,512)) -- all taps in-range
  int coreEnd = (L < 512) ? L : 512;
  int base = twop;
  for (; base + 128 <= coreEnd; base += 128) {
    const float* p = xr + (base - twop) + 2 * lane;
    float a0 = bv, a1 = bv;
    int off = 0;
    #pragma unroll
    for (int j = 0; j < KS; ++j) {
      a0 = fmaf(wv[j], p[off], a0);
      a1 = fmaf(wv[j], p[off + 1], a1);
      off += dil;
    }
    vmax = fmaxf(vmax, fmaxf(a0, a1));
    cnt += (a0 > 0.0f); cnt += (a1 > 0.0f);
  }
  for (int t = base + lane; t < coreEnd; t += 64) {   // scalar core tail (<128 t)
    float acc = bv;
    const float* p = xr + (t - twop);
    int idx = 0;
    #pragma unroll
    for (int j = 0; j < KS; ++j) { acc = fmaf(wv[j], p[idx], acc); idx += dil; }
    vmax = fmaxf(vmax, acc);
    cnt += (acc > 0.0f);
  }
  // guarded epilogue: t in [512, L)   (empty when pad==0)
  for (int t = 512 + lane; t < L; t += 64) {
    float acc = bv;
    int idx = t - twop;
    #pragma unroll
    for (int j = 0; j < KS; ++j) {
      int ci = idx > 511 ? 511 : idx;
      acc = fmaf(wv[j], ((unsigned)idx < 512u) ? xr[ci] : 0.0f, acc);
      idx += dil;
    }
    vmax = fmaxf(vmax, acc);
    cnt += (acc > 0.0f);
  }
}

__global__ __launch_bounds__(512) void conv_feat_k(const float* __restrict__ x,
                                                   const float* __restrict__ W,
                                                   const float* __restrict__ bias,
                                                   const uint16_t* __restrict__ cand,
                                                   float* __restrict__ out) {
  __shared__ float xs[16 * 512];
  int k = blockIdx.x;
  int tid = threadIdx.x;
  const float4* x4 = (const float4*)x;
  float4* xs4 = (float4*)xs;
  #pragma unroll
  for (int i = 0; i < 4; ++i)
    xs4[tid + 512 * i] = x4[tid + 512 * i];

  int sel = g_sel;
  float diag = g_diag;
  int ks = 0, dil = 1, twop = 0, L = 1;
  if (sel >= 0) {
    uint32_t wd = cand[sel * NK + k];
    ks  = 7 + 2 * (int)(wd & 3);
    dil = (int)((wd >> 2) & 127);
    int pad = (int)(wd >> 9);
    twop = (ks - 1) * dil * pad;
    L = 512 + 2 * twop - dil * (ks - 1);
    // self-validation fallback (redundant with select_k, costs nothing)
    float w10 = W[k * 11 + 10], w8 = W[k * 11 + 8];
    int ksW = (w10 != 0.0f) ? 11 : ((w8 != 0.0f) ? 9 : 7);
    if (ks != ksW) { ks = 0; diag = 6500000.0f; }
  }
  float wv[11];
  #pragma unroll
  for (int j = 0; j < 11; ++j) wv[j] = W[k * 11 + j];
  float bv = bias[k];
  __syncthreads();

  int wave = tid >> 6, lane = tid & 63;
  if (ks == 0) {   // diagnostic path (never taken when RNG matches)
    for (int bb = wave; bb < 16; bb += 8)
      if (lane == 0) {
        out[(size_t)bb * 20000 + 2 * k]     = diag;
        out[(size_t)bb * 20000 + 2 * k + 1] = diag;
      }
    return;
  }
  for (int bb = wave; bb < 16; bb += 8) {
    const float* xr = xs + bb * 512;
    float vmax = -INFINITY;
    int cnt = 0;
    if (ks == 7)       conv_batch<7>(xr, wv, bv, twop, dil, L, lane, vmax, cnt);
    else if (ks == 9)  conv_batch<9>(xr, wv, bv, twop, dil, L, lane, vmax, cnt);
    else               conv_batch<11>(xr, wv, bv, twop, dil, L, lane, vmax, cnt);
    #pragma unroll
    for (int off = 32; off >= 1; off >>= 1) {
      vmax = fmaxf(vmax, __shfl_xor(vmax, off));
      cnt += __shfl_xor(cnt, off);
    }
    if (lane == 0) {
      out[(size_t)bb * 20000 + 2 * k]     = vmax;
      out[(size_t)bb * 20000 + 2 * k + 1] = (float)cnt / (float)L;
    }
  }
}

extern "C" void kernel_launch(void* const* d_in, const int* in_sizes, int n_in,
                              void* d_out, int out_size, void* d_ws, size_t ws_size,
                              hipStream_t stream) {
  (void)out_size; (void)ws_size;
  const float *x = nullptr, *W = nullptr, *bias = nullptr;
  for (int i = 0; i < n_in; ++i) {
    int sz = in_sizes[i];
    if (sz == 16 * 512)      x    = (const float*)d_in[i];
    else if (sz == NK * 11)  W    = (const float*)d_in[i];
    else if (sz == NK)       bias = (const float*)d_in[i];
  }
  float failDiag = 0.0f;
  if (!x || !W || !bias) {
    failDiag = 9000000.0f;
    x = (const float*)d_in[0]; W = (const float*)d_in[1]; bias = (const float*)d_in[2];
  }

  static uint64_t s_sub[NDRAW];
  build_stream(s_sub);

  // d0 oracle: default_rng(0).random() == 0.6369616873214543 (verified r8)
  double d0 = (double)(s_sub[0] >> 11) * (1.0 / 9007199254740992.0);
  if (failDiag == 0.0f && fabs(d0 - 0.6369616873214543) >= 1.0e-15)
    failDiag = 4000000.0f;

  // 3 candidate rows, priority: {Lemire32-lo (truth), Lemire32-hi, Lemire64}
  static uint16_t h_cand[NROW * NK];
  gen_combo(s_sub, 0, h_cand + 0 * NK);
  gen_combo(s_sub, 2, h_cand + 1 * NK);
  gen_combo(s_sub, 1, h_cand + 2 * NK);

  hipMemcpyAsync(d_ws, h_cand, sizeof(h_cand), hipMemcpyHostToDevice, stream);
  select_k<<<1, 1024, 0, stream>>>(W, (const uint16_t*)d_ws, failDiag);
  conv_feat_k<<<NK, 512, 0, stream>>>(x, W, bias, (const uint16_t*)d_ws, (float*)d_out);
}

// Round 13
// 143.244 us; speedup vs baseline: 1.2968x; 1.2628x over previous
//
#include <hip/hip_runtime.h>
#include <math.h>
#include <stdint.h>

typedef unsigned __int128 u128;

#define NK 10000
#define NDRAW 30100
#define NROW 3

#define PCG_MUL_128 ((((u128)0x2360ed051fc65da4ULL) << 64) | 0x4385df649fccf645ULL)

__device__ int   g_sel;
__device__ float g_diag;

// ============================================================================
// HOST-SIDE numpy default_rng(0) chain (verified r8-r12):
// SeedSequence mix() = x*L - y*R (SUBTRACT); PCG64 XSL-RR step-then-output;
// integers() -> buffered Lemire32, low half first (r12-selected row 0).
// ============================================================================
static void build_stream(uint64_t* out) {
  uint32_t w[8];
  uint32_t hc = 0x43b0d7e5u;                                  // INIT_A
  auto hashmix = [&hc](uint32_t v) -> uint32_t {
    v ^= hc; hc *= 0x931e8875u; v *= hc; v ^= v >> 16; return v;   // MULT_A
  };
  uint32_t pool[4];
  for (int i = 0; i < 4; ++i) pool[i] = hashmix(0u);          // entropy=[0]
  for (int s = 0; s < 4; ++s)
    for (int d = 0; d < 4; ++d)
      if (s != d) {
        uint32_t h = hashmix(pool[s]);
        uint32_t r = pool[d] * 0xca01f9ddu - h * 0x4973f715u; // MIX: subtract
        r ^= r >> 16;
        pool[d] = r;
      }
  uint32_t hb = 0x8b51f9ddu;                                  // INIT_B
  for (int i = 0; i < 8; ++i) {
    uint32_t v = pool[i & 3];
    v ^= hb; hb *= 0x58f38dedu; v *= hb; v ^= v >> 16;        // MULT_B
    w[i] = v;
  }
  uint64_t A = (uint64_t)w[0] | ((uint64_t)w[1] << 32);
  uint64_t B = (uint64_t)w[2] | ((uint64_t)w[3] << 32);
  uint64_t C = (uint64_t)w[4] | ((uint64_t)w[5] << 32);
  uint64_t D = (uint64_t)w[6] | ((uint64_t)w[7] << 32);
  u128 initstate = ((u128)A << 64) | B;
  u128 initseq   = ((u128)C << 64) | D;
  u128 inc = (initseq << 1) | (u128)1;
  u128 st  = inc;                    // srandom from state=0
  st += initstate;
  st = st * PCG_MUL_128 + inc;
  for (int i = 0; i < NDRAW; ++i) {  // step-then-output XSL-RR
    st = st * PCG_MUL_128 + inc;
    uint64_t x = (uint64_t)(st >> 64) ^ (uint64_t)st;
    unsigned r = (unsigned)(st >> 122);
    out[i] = (x >> r) | (x << ((64u - r) & 63u));
  }
}

struct HCur { const uint64_t* s; int pos; int has; uint32_t buf; int hifirst; };
static inline uint32_t hnext32(HCur& c) {
  if (c.has) { c.has = 0; return c.buf; }
  uint64_t v = c.s[c.pos++]; c.has = 1;
  if (c.hifirst) { c.buf = (uint32_t)v; return (uint32_t)(v >> 32); }
  c.buf = (uint32_t)(v >> 32); return (uint32_t)v;
}

static int t_ks[NK];
// structures: 0 = Lemire32-lo (numpy truth), 2 = Lemire32-hi, 1 = Lemire64
static void gen_combo(const uint64_t* st, int s, uint16_t* dst) {
  HCur c{st, 0, 0, 0, (s == 2) ? 1 : 0};
  for (int i = 0; i < NK; ++i) {          // Phase 1: integers(0,3), Lemire
    if (s == 1)      { u128 m; do { m = (u128)st[c.pos++] * 3; } while ((uint64_t)m == 0);
                       t_ks[i] = (int)(uint64_t)(m >> 64); }
    else             { uint64_t m; do { m = (uint64_t)hnext32(c) * 3ull; } while ((uint32_t)m == 0u);
                       t_ks[i] = (int)(m >> 32); }
  }
  c.has = 0;
  for (int i = 0; i < NK; ++i) {          // Phase 2: uniform(0,hi) -> floor(2**u)
    double d = (double)(st[c.pos++] >> 11) * (1.0 / 9007199254740992.0);
    int ks = 7 + 2 * t_ks[i];
    int m  = 511 / (ks - 1);              // 85 / 63 / 51
    double u = log2((double)m) * d;       // glibc == numpy's libm
    int dil = (int)floor(pow(2.0, u));    // 1..84
    dst[i] = (uint16_t)((uint32_t)t_ks[i] | ((uint32_t)(dil & 127) << 2));
  }
  c.has = 0;
  for (int i = 0; i < NK; ++i) {          // Phase 3: integers(0,2): MSB, no reject
    int pad;
    if (s == 1) pad = (int)(st[c.pos++] >> 63);
    else        pad = (int)(hnext32(c) >> 31);
    dst[i] = (uint16_t)(dst[i] | ((uint32_t)pad << 9));
  }
}

// ============================================================================
// Device: selection only -- first row matching ks ground truth from W
// ============================================================================
__global__ __launch_bounds__(1024) void select_k(const float* __restrict__ W,
                                                 const uint16_t* __restrict__ cand,
                                                 float failDiag) {
  __shared__ int ksW[NK];
  __shared__ int mism[NROW];
  int tid = threadIdx.x;
  for (int i = tid; i < NK; i += 1024) {
    float w10 = W[i * 11 + 10], w8 = W[i * 11 + 8];
    ksW[i] = (w10 != 0.0f) ? 11 : ((w8 != 0.0f) ? 9 : 7);
  }
  if (tid < NROW) mism[tid] = 0;
  __syncthreads();
  for (int c = 0; c < NROW; ++c) {
    int bad = 0;
    for (int i = tid; i < NK; i += 1024) {
      int ks = 7 + 2 * (int)(cand[c * NK + i] & 3);
      if (ks != ksW[i]) { bad = 1; break; }
    }
    if (bad) atomicExch(&mism[c], 1);
  }
  __syncthreads();
  if (tid == 0) {
    int sel = -1;
    for (int c = 0; c < NROW; ++c) if (!mism[c]) { sel = c; break; }
    g_sel = sel;
    g_diag = (sel >= 0) ? 0.0f : ((failDiag != 0.0f) ? failDiag : 6000000.0f);
  }
}

// ============================================================================
// Main conv + max/ppv kernel: one block (512 thr, 8 waves) per output kernel k.
// LDS holds x BATCH-TRANSPOSED: xs[t][b] (t=0..512, row 512 = zeros).
// Each lane (tl,bg) reads float4 = batches 4bg..4bg+3 at one t via
// ds_read_b128 -- wave addresses form one contiguous 1024B block (conflict-
// free). Pad/clamp = umin(idx,512) -> zero row. 4x fewer DS insts than r9.
// ============================================================================
template<int KS>
__device__ __forceinline__ void conv_core(const float4* __restrict__ xs4,
                                          const float* wv, float bv,
                                          int twop, int dil, int L,
                                          int wave, int tl, int bg,
                                          float* m, int* cn) {
  int nch = (L + 15) >> 4;
  for (int c = wave; c < nch; c += 8) {
    int t = (c << 4) + tl;
    int idx = t - twop;
    float a0 = bv, a1 = bv, a2 = bv, a3 = bv;
    #pragma unroll
    for (int j = 0; j < KS; ++j) {
      unsigned ci = (unsigned)idx;
      ci = (ci > 512u) ? 512u : ci;        // umin: negatives wrap -> zero row
      float4 v = xs4[ci * 4 + bg];
      float wj = wv[j];
      a0 = fmaf(wj, v.x, a0);
      a1 = fmaf(wj, v.y, a1);
      a2 = fmaf(wj, v.z, a2);
      a3 = fmaf(wj, v.w, a3);
      idx += dil;
    }
    if (t < L) {
      m[0] = fmaxf(m[0], a0); cn[0] += (a0 > 0.0f);
      m[1] = fmaxf(m[1], a1); cn[1] += (a1 > 0.0f);
      m[2] = fmaxf(m[2], a2); cn[2] += (a2 > 0.0f);
      m[3] = fmaxf(m[3], a3); cn[3] += (a3 > 0.0f);
    }
  }
}

__global__ __launch_bounds__(512) void conv_feat_k(const float* __restrict__ x,
                                                   const float* __restrict__ W,
                                                   const float* __restrict__ bias,
                                                   const uint16_t* __restrict__ cand,
                                                   float* __restrict__ out) {
  __shared__ float xs[513 * 16];     // xs[t][b], row 512 = zeros (32.06 KB)
  __shared__ float smax[8 * 16];     // per-wave partials
  __shared__ int   scnt[8 * 16];
  float4* xs4 = (float4*)xs;
  int k = blockIdx.x;
  int tid = threadIdx.x;

  // stage batch-transposed: thread -> (t, bq); write = contiguous b128
  #pragma unroll
  for (int q = 0; q < 4; ++q) {
    int flat = q * 512 + tid;        // = t*4 + bq
    int t = flat >> 2, bq = flat & 3;
    float4 v;
    v.x = x[(4 * bq + 0) * 512 + t];
    v.y = x[(4 * bq + 1) * 512 + t];
    v.z = x[(4 * bq + 2) * 512 + t];
    v.w = x[(4 * bq + 3) * 512 + t];
    xs4[flat] = v;
  }
  if (tid < 4) xs4[512 * 4 + tid] = make_float4(0.f, 0.f, 0.f, 0.f);

  int sel = g_sel;
  float diag = g_diag;
  int ks = 0, dil = 1, twop = 0, L = 1;
  if (sel >= 0) {
    uint32_t wd = cand[sel * NK + k];
    ks  = 7 + 2 * (int)(wd & 3);
    dil = (int)((wd >> 2) & 127);
    int pad = (int)(wd >> 9);
    twop = (ks - 1) * dil * pad;
    L = 512 + 2 * twop - dil * (ks - 1);
    float w10 = W[k * 11 + 10], w8 = W[k * 11 + 8];
    int ksW = (w10 != 0.0f) ? 11 : ((w8 != 0.0f) ? 9 : 7);
    if (ks != ksW) { ks = 0; diag = 6500000.0f; }   // self-validation fallback
  }
  float wv[11];
  #pragma unroll
  for (int j = 0; j < 11; ++j) wv[j] = W[k * 11 + j];
  float bv = bias[k];
  __syncthreads();

  if (ks == 0) {   // diagnostic path (never taken when RNG matches)
    if (tid < 16) {
      out[(size_t)tid * 20000 + 2 * k]     = diag;
      out[(size_t)tid * 20000 + 2 * k + 1] = diag;
    }
    return;
  }

  int wave = tid >> 6, lane = tid & 63;
  int tl = lane >> 2, bg = lane & 3;
  float m[4] = {-INFINITY, -INFINITY, -INFINITY, -INFINITY};
  int cn[4] = {0, 0, 0, 0};

  if (ks == 7)       conv_core<7>(xs4, wv, bv, twop, dil, L, wave, tl, bg, m, cn);
  else if (ks == 9)  conv_core<9>(xs4, wv, bv, twop, dil, L, wave, tl, bg, m, cn);
  else               conv_core<11>(xs4, wv, bv, twop, dil, L, wave, tl, bg, m, cn);

  // reduce over tl (lane bits 2..5), keep bg
  #pragma unroll
  for (int off = 4; off <= 32; off <<= 1) {
    #pragma unroll
    for (int r = 0; r < 4; ++r) {
      m[r] = fmaxf(m[r], __shfl_xor(m[r], off));
      cn[r] += __shfl_xor(cn[r], off);
    }
  }
  if (tl == 0) {
    #pragma unroll
    for (int r = 0; r < 4; ++r) {
      smax[wave * 16 + 4 * bg + r] = m[r];
      scnt[wave * 16 + 4 * bg + r] = cn[r];
    }
  }
  __syncthreads();
  if (tid < 16) {
    float mm = -INFINITY; int cc = 0;
    #pragma unroll
    for (int w2 = 0; w2 < 8; ++w2) {
      mm = fmaxf(mm, smax[w2 * 16 + tid]);
      cc += scnt[w2 * 16 + tid];
    }
    out[(size_t)tid * 20000 + 2 * k]     = mm;
    out[(size_t)tid * 20000 + 2 * k + 1] = (float)cc / (float)L;
  }
}

extern "C" void kernel_launch(void* const* d_in, const int* in_sizes, int n_in,
                              void* d_out, int out_size, void* d_ws, size_t ws_size,
                              hipStream_t stream) {
  (void)out_size; (void)ws_size;
  const float *x = nullptr, *W = nullptr, *bias = nullptr;
  for (int i = 0; i < n_in; ++i) {
    int sz = in_sizes[i];
    if (sz == 16 * 512)      x    = (const float*)d_in[i];
    else if (sz == NK * 11)  W    = (const float*)d_in[i];
    else if (sz == NK)       bias = (const float*)d_in[i];
  }
  float failDiag = 0.0f;
  if (!x || !W || !bias) {
    failDiag = 9000000.0f;
    x = (const float*)d_in[0]; W = (const float*)d_in[1]; bias = (const float*)d_in[2];
  }

  static uint64_t s_sub[NDRAW];
  build_stream(s_sub);

  // d0 oracle: default_rng(0).random() == 0.6369616873214543 (verified r8)
  double d0 = (double)(s_sub[0] >> 11) * (1.0 / 9007199254740992.0);
  if (failDiag == 0.0f && fabs(d0 - 0.6369616873214543) >= 1.0e-15)
    failDiag = 4000000.0f;

  // 3 candidate rows, priority: {Lemire32-lo (truth), Lemire32-hi, Lemire64}
  static uint16_t h_cand[NROW * NK];
  gen_combo(s_sub, 0, h_cand + 0 * NK);
  gen_combo(s_sub, 2, h_cand + 1 * NK);
  gen_combo(s_sub, 1, h_cand + 2 * NK);

  hipMemcpyAsync(d_ws, h_cand, sizeof(h_cand), hipMemcpyHostToDevice, stream);
  select_k<<<1, 1024, 0, stream>>>(W, (const uint16_t*)d_ws, failDiag);
  conv_feat_k<<<NK, 512, 0, stream>>>(x, W, bias, (const uint16_t*)d_ws, (float*)d_out);
}